// Round 7
// baseline (1179.049 us; speedup 1.0000x reference)
//
#include <hip/hip_runtime.h>
#include <cstddef>
#include <cstdint>

// ---------------- problem constants ----------------
#define T_TOK 4096      // BATCH*SEQ
#define DIM   1024
#define HID   2816
#define NE    8
#define TOPK  2
#define CAP   9216      // 72 row-tiles * 128
#define NRT   72        // CAP / BM
#define BM    128
#define BN    64
#define BK    32

// ---------------- workspace layout (bytes) ----------------
#define WS_COUNTS  0
#define WS_CURSORS 64
#define WS_OFFSETS 128
#define WS_TILE_E  256
#define WS_SEL     1024                       // T*2 int
#define WS_WTS     33792                      // T*2 float
#define WS_ATOK    66560                      // CAP int
#define WS_AW      103424                     // CAP float
#define WS_XHI     140288                     // 4096*1024 ushort  (8.39 MB)
#define WS_XLO     8528896                    // same
#define WS_IMG     16917504                   // w1img | w3img | w2img | himg (per chunk)
// per-chunk sizes (bytes): w1img = w3img = w2img = CH*32768 ; himg = CH*36864

typedef __attribute__((ext_vector_type(8))) short bf16x8;
typedef __attribute__((ext_vector_type(8))) unsigned short u16x8;
typedef __attribute__((ext_vector_type(4))) float f32x4;

// async global->LDS, 16B per lane; LDS dst is wave-uniform base + lane*16
#define GL16(gp, lp) __builtin_amdgcn_global_load_lds( \
    (const __attribute__((address_space(1))) unsigned int*)(gp), \
    (__attribute__((address_space(3))) unsigned int*)(lp), 16, 0, 0)

__device__ __forceinline__ unsigned short f2bf(float f) {
  unsigned int u = __builtin_bit_cast(unsigned int, f);
  unsigned int r = u + 0x7FFFu + ((u >> 16) & 1u);
  return (unsigned short)(r >> 16);
}
__device__ __forceinline__ float bf2f(unsigned short s) {
  unsigned int u = ((unsigned int)s) << 16;
  return __builtin_bit_cast(float, u);
}
__device__ __forceinline__ void split2(float f, unsigned short& hi, unsigned short& lo) {
  hi = f2bf(f);
  lo = f2bf(f - bf2f(hi));
}

// ---------------- gating (unchanged) ----------------
__global__ __launch_bounds__(256) void gate_kernel(
    const float* __restrict__ x, const float* __restrict__ gw,
    int* __restrict__ sel, float* __restrict__ wts, int* __restrict__ counts)
{
  const int wave = threadIdx.x >> 6;
  const int lane = threadIdx.x & 63;
  const int t = blockIdx.x * 4 + wave;
  const float* xr = x + (size_t)t * DIM;
  float acc[NE] = {0.f, 0.f, 0.f, 0.f, 0.f, 0.f, 0.f, 0.f};
#pragma unroll 4
  for (int j = 0; j < DIM / 64; ++j) {
    const int d = lane + 64 * j;
    const float xv = xr[d];
#pragma unroll
    for (int e = 0; e < NE; ++e) acc[e] = fmaf(xv, gw[e * DIM + d], acc[e]);
  }
#pragma unroll
  for (int m = 32; m > 0; m >>= 1) {
#pragma unroll
    for (int e = 0; e < NE; ++e) acc[e] += __shfl_xor(acc[e], m, 64);
  }
  if (lane == 0) {
    float mx = acc[0];
#pragma unroll
    for (int e = 1; e < NE; ++e) mx = fmaxf(mx, acc[e]);
    float ex[NE];
#pragma unroll
    for (int e = 0; e < NE; ++e) ex[e] = __expf(acc[e] - mx);
    int e0 = 0; float p0 = ex[0];
#pragma unroll
    for (int e = 1; e < NE; ++e) if (ex[e] > p0) { p0 = ex[e]; e0 = e; }
    int e1 = -1; float p1 = -1.f;
#pragma unroll
    for (int e = 0; e < NE; ++e) if (e != e0 && ex[e] > p1) { p1 = ex[e]; e1 = e; }
    const float inv = 1.f / (p0 + p1);
    sel[2 * t + 0] = e0; sel[2 * t + 1] = e1;
    wts[2 * t + 0] = p0 * inv; wts[2 * t + 1] = p1 * inv;
    atomicAdd(&counts[e0], 1);
    atomicAdd(&counts[e1], 1);
  }
}

// ---------------- offsets (128-aligned regions) ----------------
__global__ void offsets_kernel(const int* __restrict__ counts,
                               int* __restrict__ offsets, int* __restrict__ cursors,
                               int* __restrict__ tile_e)
{
  if (threadIdx.x == 0 && blockIdx.x == 0) {
    int off = 0;
    for (int e = 0; e < NE; ++e) {
      offsets[e] = off;
      cursors[e] = off;
      off += (counts[e] + 127) & ~127;
    }
    offsets[NE] = off;
    for (int t = 0; t < NRT; ++t) {
      const int r = t * BM;
      int ee = 0;
      while (ee < NE - 1 && r >= offsets[ee + 1]) ++ee;
      tile_e[t] = ee;
    }
  }
}

// ---------------- scatter (unchanged) ----------------
__global__ __launch_bounds__(256) void scatter_kernel(
    const int* __restrict__ sel, const float* __restrict__ wts,
    int* __restrict__ cursors, int* __restrict__ atok, float* __restrict__ aw)
{
  const int t = blockIdx.x * 256 + threadIdx.x;
  if (t < T_TOK) {
#pragma unroll
    for (int k = 0; k < TOPK; ++k) {
      const int e = sel[2 * t + k];
      const int pos = atomicAdd(&cursors[e], 1);
      atok[pos] = t;
      aw[pos] = wts[2 * t + k];
    }
  }
}

// ---------------- prepass: x -> bf16 hi/lo row-major images ----------------
__global__ __launch_bounds__(256) void convert_x_kernel(
    const float* __restrict__ x, unsigned short* __restrict__ xhi,
    unsigned short* __restrict__ xlo)
{
  const size_t t = (size_t)blockIdx.x * 256 + threadIdx.x;   // 524288 units of 8
  const float* s = x + t * 8;
  u16x8 hi, lo;
#pragma unroll
  for (int q = 0; q < 8; ++q) {
    unsigned short h, l;
    split2(s[q], h, l);
    hi[q] = h; lo[q] = l;
  }
  *(u16x8*)&xhi[t * 8] = hi;
  *(u16x8*)&xlo[t * 8] = lo;
}

// ---------------- prepass: w1/w3 chunk -> frag-ordered tile image ----------------
// tile pair = 4096 ushorts (hi 2048 | lo 2048); tile idx = (e*nct1+ct)*32 + kt
// within hi: nb*512 + ks*128 + n15*8 + j   (n = nb*16+n15 row of W, k = kt*32+ks*8+j)
__global__ __launch_bounds__(256) void convert_w13_kernel(
    const float* __restrict__ w, unsigned short* __restrict__ img,
    int hc0, int nct1)
{
  const int f = blockIdx.x * 256 + threadIdx.x;
  const int ks = f & 3;
  int t = f >> 2;
  const int n15 = t & 15; t >>= 4;
  const int nb = t & 3;   t >>= 2;
  const int kt = t & 31;  t >>= 5;
  const int ct = t % nct1;
  const int e  = t / nct1;
  const float* src = w + ((size_t)e * HID + hc0 + ct * 64 + nb * 16 + n15) * DIM + kt * 32 + ks * 8;
  u16x8 hi, lo;
#pragma unroll
  for (int q = 0; q < 8; ++q) {
    unsigned short h, l;
    split2(src[q], h, l);
    hi[q] = h; lo[q] = l;
  }
  const size_t tile = ((size_t)(e * nct1 + ct) * 32 + kt) * 4096;
  const int off = nb * 512 + ks * 128 + n15 * 8;
  *(u16x8*)&img[tile + off] = hi;
  *(u16x8*)&img[tile + 2048 + off] = lo;
}

// ---------------- prepass: w2 chunk -> frag-ordered tile image ----------------
// tile idx = (e*16+ct2)*nkt2 + kt ; n = ct2*64+nb*16+n15 (DIM), k = kt*32+ks*8+j (chunk)
__global__ __launch_bounds__(256) void convert_w2_kernel(
    const float* __restrict__ w2, unsigned short* __restrict__ img,
    int hc0, int nkt2)
{
  const int f = blockIdx.x * 256 + threadIdx.x;
  const int n15 = f & 15;
  int t = f >> 4;
  const int ks = t & 3; t >>= 2;
  const int nb = t & 3; t >>= 2;
  const int kt = t % nkt2; t /= nkt2;
  const int ct2 = t & 15;
  const int e = t >> 4;
  const float* src = w2 + ((size_t)e * HID + hc0 + kt * 32 + ks * 8) * DIM + ct2 * 64 + nb * 16 + n15;
  u16x8 hi, lo;
#pragma unroll
  for (int q = 0; q < 8; ++q) {
    unsigned short h, l;
    split2(src[(size_t)q * DIM], h, l);
    hi[q] = h; lo[q] = l;
  }
  const size_t tile = ((size_t)(e * 16 + ct2) * nkt2 + kt) * 4096;
  const int off = nb * 512 + ks * 128 + n15 * 8;
  *(u16x8*)&img[tile + off] = hi;
  *(u16x8*)&img[tile + 2048 + off] = lo;
}

// ---------------- GEMM1: h = silu(x W1^T) * (x W3^T), pure MFMA loop ----------------
__global__ __launch_bounds__(256) void gemm1_kernel(
    const unsigned short* __restrict__ xhi, const unsigned short* __restrict__ xlo,
    const unsigned short* __restrict__ w1img, const unsigned short* __restrict__ w3img,
    const int* __restrict__ atok, const int* __restrict__ tile_e,
    unsigned short* __restrict__ himg, int nct1)
{
  __shared__ __align__(16) unsigned short sAh[4096], sAl[4096];
  __shared__ __align__(16) unsigned short sB1h[2048], sB1l[2048], sB3h[2048], sB3l[2048];
  __shared__ int sToks[BM];

  const int orig = blockIdx.x;
  const int wg = (orig & 7) * (gridDim.x >> 3) + (orig >> 3);   // XCD-chunked (grid%8==0)
  const int ct = wg / NRT, rt = wg % NRT;
  const int nkt2 = nct1 * 2;
  const int tid = threadIdx.x, lane = tid & 63;
  const int wv = tid >> 6, wr = wv >> 1, wc = wv & 1;
  const int e = tile_e[rt];

  if (tid < BM) {
    const int tk = atok[rt * BM + tid];
    sToks[tid] = tk < 0 ? 0 : tk;
  }
  __syncthreads();

  // per-lane gather sources for A (ushort offsets into x images)
  const int rb0 = wv * 2;
  size_t asrc[2];
#pragma unroll
  for (int i = 0; i < 2; ++i) {
    const int row = (rb0 + i) * 16 + (lane & 15);
    asrc[i] = (size_t)sToks[row] * DIM + ((lane >> 4) * 8);
  }
  const size_t btile0 = ((size_t)(e * nct1 + ct) * 32) * 4096;
  const size_t boff = btile0 + wv * 512 + (size_t)lane * 8;   // hi; +2048 for lo

  const f32x4 vz = {0.f, 0.f, 0.f, 0.f};
  f32x4 acc1[4][2], acc3[4][2];
#pragma unroll
  for (int i = 0; i < 4; ++i)
#pragma unroll
    for (int j = 0; j < 2; ++j) { acc1[i][j] = vz; acc3[i][j] = vz; }

  for (int kt = 0; kt < DIM / BK; ++kt) {
    __syncthreads();                       // prev frag reads done before overwrite
#pragma unroll
    for (int i = 0; i < 2; ++i) {
      GL16(xhi + asrc[i] + kt * 32, &sAh[(rb0 + i) * 512]);
      GL16(xlo + asrc[i] + kt * 32, &sAl[(rb0 + i) * 512]);
    }
    const size_t bk = boff + (size_t)kt * 4096;
    GL16(w1img + bk,        &sB1h[wv * 512]);
    GL16(w1img + bk + 2048, &sB1l[wv * 512]);
    GL16(w3img + bk,        &sB3h[wv * 512]);
    GL16(w3img + bk + 2048, &sB3l[wv * 512]);
    __syncthreads();                       // drains vmcnt -> LDS writes visible

    bf16x8 ah[4], al[4], g1h[2], g1l[2], g3h[2], g3l[2];
#pragma unroll
    for (int ar = 0; ar < 4; ++ar) {
      const int rb = wr * 4 + ar;
      ah[ar] = *(const bf16x8*)&sAh[rb * 512 + lane * 8];
      al[ar] = *(const bf16x8*)&sAl[rb * 512 + lane * 8];
    }
#pragma unroll
    for (int bc = 0; bc < 2; ++bc) {
      const int cb = wc * 2 + bc;
      g1h[bc] = *(const bf16x8*)&sB1h[cb * 512 + lane * 8];
      g1l[bc] = *(const bf16x8*)&sB1l[cb * 512 + lane * 8];
      g3h[bc] = *(const bf16x8*)&sB3h[cb * 512 + lane * 8];
      g3l[bc] = *(const bf16x8*)&sB3l[cb * 512 + lane * 8];
    }
#pragma unroll
    for (int ar = 0; ar < 4; ++ar)
#pragma unroll
      for (int bc = 0; bc < 2; ++bc) {
        acc1[ar][bc] = __builtin_amdgcn_mfma_f32_16x16x32_bf16(ah[ar], g1h[bc], acc1[ar][bc], 0, 0, 0);
        acc1[ar][bc] = __builtin_amdgcn_mfma_f32_16x16x32_bf16(ah[ar], g1l[bc], acc1[ar][bc], 0, 0, 0);
        acc1[ar][bc] = __builtin_amdgcn_mfma_f32_16x16x32_bf16(al[ar], g1h[bc], acc1[ar][bc], 0, 0, 0);
        acc3[ar][bc] = __builtin_amdgcn_mfma_f32_16x16x32_bf16(ah[ar], g3h[bc], acc3[ar][bc], 0, 0, 0);
        acc3[ar][bc] = __builtin_amdgcn_mfma_f32_16x16x32_bf16(ah[ar], g3l[bc], acc3[ar][bc], 0, 0, 0);
        acc3[ar][bc] = __builtin_amdgcn_mfma_f32_16x16x32_bf16(al[ar], g3h[bc], acc3[ar][bc], 0, 0, 0);
      }
  }

  // epilogue: silu*u, split, write h as frag-ordered hi/lo tiles for gemm2's A
  const size_t hbase = ((size_t)rt * nkt2 + (ct * 2 + wc)) * 8192;   // tile pair = 8192 us
#pragma unroll
  for (int ar = 0; ar < 4; ++ar)
#pragma unroll
    for (int bc = 0; bc < 2; ++bc)
#pragma unroll
      for (int r = 0; r < 4; ++r) {
        const float g = acc1[ar][bc][r];
        const float u = acc3[ar][bc][r];
        const float s = g / (1.f + __expf(-g));
        unsigned short h_, l_;
        split2(s * u, h_, l_);
        const int idx = (wr * 4 + ar) * 512 + (bc * 2 + ((lane >> 3) & 1)) * 128
                      + ((lane >> 4) * 4 + r) * 8 + (lane & 7);
        himg[hbase + idx] = h_;
        himg[hbase + 4096 + idx] = l_;
      }
}

// ---------------- GEMM2: y += (h W2) * route_weight ----------------
__global__ __launch_bounds__(256) void gemm2_kernel(
    const unsigned short* __restrict__ himg, const unsigned short* __restrict__ w2img,
    const int* __restrict__ atok, const float* __restrict__ aw,
    const int* __restrict__ tile_e, float* __restrict__ y, int nkt2)
{
  __shared__ __align__(16) unsigned short sAh[4096], sAl[4096];
  __shared__ __align__(16) unsigned short sBh[2048], sBl[2048];

  const int orig = blockIdx.x;
  const int wg = (orig & 7) * (gridDim.x >> 3) + (orig >> 3);
  const int ct2 = wg / NRT, rt = wg % NRT;
  const int tid = threadIdx.x, lane = tid & 63;
  const int wv = tid >> 6, wr = wv >> 1, wc = wv & 1;
  const int e = tile_e[rt];

  const int rb0 = wv * 2;
  const size_t atile0 = (size_t)rt * nkt2 * 8192;
  const size_t btile0 = ((size_t)(e * 16 + ct2) * nkt2) * 4096;
  const size_t lane8 = (size_t)lane * 8;

  const f32x4 vz = {0.f, 0.f, 0.f, 0.f};
  f32x4 acc[4][2];
#pragma unroll
  for (int i = 0; i < 4; ++i)
#pragma unroll
    for (int j = 0; j < 2; ++j) acc[i][j] = vz;

  for (int kt = 0; kt < nkt2; ++kt) {
    __syncthreads();
    const size_t ab = atile0 + (size_t)kt * 8192;
#pragma unroll
    for (int i = 0; i < 2; ++i) {
      GL16(himg + ab + (rb0 + i) * 512 + lane8,        &sAh[(rb0 + i) * 512]);
      GL16(himg + ab + 4096 + (rb0 + i) * 512 + lane8, &sAl[(rb0 + i) * 512]);
    }
    const size_t bb = btile0 + (size_t)kt * 4096 + wv * 512 + lane8;
    GL16(w2img + bb,        &sBh[wv * 512]);
    GL16(w2img + bb + 2048, &sBl[wv * 512]);
    __syncthreads();

    bf16x8 ah[4], al[4], bh_[2], bl_[2];
#pragma unroll
    for (int ar = 0; ar < 4; ++ar) {
      const int rb = wr * 4 + ar;
      ah[ar] = *(const bf16x8*)&sAh[rb * 512 + lane * 8];
      al[ar] = *(const bf16x8*)&sAl[rb * 512 + lane * 8];
    }
#pragma unroll
    for (int bc = 0; bc < 2; ++bc) {
      const int cb = wc * 2 + bc;
      bh_[bc] = *(const bf16x8*)&sBh[cb * 512 + lane * 8];
      bl_[bc] = *(const bf16x8*)&sBl[cb * 512 + lane * 8];
    }
#pragma unroll
    for (int ar = 0; ar < 4; ++ar)
#pragma unroll
      for (int bc = 0; bc < 2; ++bc) {
        acc[ar][bc] = __builtin_amdgcn_mfma_f32_16x16x32_bf16(ah[ar], bh_[bc], acc[ar][bc], 0, 0, 0);
        acc[ar][bc] = __builtin_amdgcn_mfma_f32_16x16x32_bf16(ah[ar], bl_[bc], acc[ar][bc], 0, 0, 0);
        acc[ar][bc] = __builtin_amdgcn_mfma_f32_16x16x32_bf16(al[ar], bh_[bc], acc[ar][bc], 0, 0, 0);
      }
  }

#pragma unroll
  for (int ar = 0; ar < 4; ++ar)
#pragma unroll
    for (int r = 0; r < 4; ++r) {
      const int grow = rt * BM + wr * 64 + ar * 16 + (lane >> 4) * 4 + r;
      const int tok = atok[grow];
      if (tok >= 0) {
        const float wgt = aw[grow];
#pragma unroll
        for (int bc = 0; bc < 2; ++bc) {
          const int col = ct2 * BN + wc * 32 + bc * 16 + (lane & 15);
          atomicAdd(y + (size_t)tok * DIM + col, acc[ar][bc][r] * wgt);
        }
      }
    }
}

// ---------------- launch ----------------
extern "C" void kernel_launch(void* const* d_in, const int* in_sizes, int n_in,
                              void* d_out, int out_size, void* d_ws, size_t ws_size,
                              hipStream_t stream) {
  const float* x  = (const float*)d_in[0];
  const float* w1 = (const float*)d_in[1];
  const float* w2 = (const float*)d_in[2];
  const float* w3 = (const float*)d_in[3];
  const float* gw = (const float*)d_in[4];
  float* y = (float*)d_out;

  char* ws = (char*)d_ws;
  int*   counts  = (int*)(ws + WS_COUNTS);
  int*   cursors = (int*)(ws + WS_CURSORS);
  int*   offsets = (int*)(ws + WS_OFFSETS);
  int*   tile_e  = (int*)(ws + WS_TILE_E);
  int*   sel     = (int*)(ws + WS_SEL);
  float* wts     = (float*)(ws + WS_WTS);
  int*   atok    = (int*)(ws + WS_ATOK);
  float* aw      = (float*)(ws + WS_AW);
  unsigned short* xhi = (unsigned short*)(ws + WS_XHI);
  unsigned short* xlo = (unsigned short*)(ws + WS_XLO);

  // largest hidden-chunk (divides 2816, %64==0) fitting the image workspace
  static const int chs[6] = {2816, 1408, 704, 256, 128, 64};
  int CH = 64;
  for (int i = 0; i < 6; ++i) {
    const size_t need = (size_t)WS_IMG + (size_t)chs[i] * 135168ull;
    if (need <= ws_size) { CH = chs[i]; break; }
  }
  const int nct1 = CH / 64, nkt2 = CH / 32;
  const size_t wimg_b = (size_t)CH * 32768ull;
  unsigned short* w1img = (unsigned short*)(ws + WS_IMG);
  unsigned short* w3img = (unsigned short*)(ws + WS_IMG + wimg_b);
  unsigned short* w2img = (unsigned short*)(ws + WS_IMG + 2 * wimg_b);
  unsigned short* himg  = (unsigned short*)(ws + WS_IMG + 3 * wimg_b);

  hipMemsetAsync(counts, 0, 8 * sizeof(int), stream);
  hipMemsetAsync(atok, 0xFF, CAP * sizeof(int), stream);
  hipMemsetAsync(y, 0, (size_t)T_TOK * DIM * sizeof(float), stream);

  gate_kernel<<<T_TOK / 4, 256, 0, stream>>>(x, gw, sel, wts, counts);
  offsets_kernel<<<1, 64, 0, stream>>>(counts, offsets, cursors, tile_e);
  scatter_kernel<<<T_TOK / 256, 256, 0, stream>>>(sel, wts, cursors, atok, aw);
  convert_x_kernel<<<(T_TOK * DIM / 8) / 256, 256, 0, stream>>>(x, xhi, xlo);

  for (int hc0 = 0; hc0 < HID; hc0 += CH) {
    const int wblk = 8 * nct1 * 32;           // = CH*4 blocks of 256
    convert_w13_kernel<<<wblk, 256, 0, stream>>>(w1, w1img, hc0, nct1);
    convert_w13_kernel<<<wblk, 256, 0, stream>>>(w3, w3img, hc0, nct1);
    convert_w2_kernel<<<128 * nkt2, 256, 0, stream>>>(w2, w2img, hc0, nkt2);
    gemm1_kernel<<<NRT * nct1, 256, 0, stream>>>(xhi, xlo, w1img, w3img, atok, tile_e, himg, nct1);
    gemm2_kernel<<<NRT * 16, 256, 0, stream>>>(himg, w2img, atok, aw, tile_e, y, nkt2);
  }
}

// Round 9
// 1110.787 us; speedup vs baseline: 1.0615x; 1.0615x over previous
//
#include <hip/hip_runtime.h>
#include <cstddef>
#include <cstdint>

// ---------------- problem constants ----------------
#define T_TOK 4096      // BATCH*SEQ
#define DIM   1024
#define HID   2816
#define NE    8
#define TOPK  2
#define CAP   9216      // 72 row-tiles * 128
#define NRT   72        // CAP / BM
#define BM    128
#define BN    64
#define BK    32

// ---------------- workspace layout (bytes) ----------------
#define WS_COUNTS  0
#define WS_CURSORS 64
#define WS_OFFSETS 128
#define WS_TILE_E  256
#define WS_SEL     1024                       // T*2 int
#define WS_WTS     33792                      // T*2 float
#define WS_ATOK    66560                      // CAP int
#define WS_AW      103424                     // CAP float
#define WS_XHI     140288                     // 4096*1024 ushort  (8.39 MB)
#define WS_XLO     8528896                    // same
#define WS_IMG     16917504                   // w1img | w3img | w2img | himg (per chunk)
// per-chunk sizes (bytes): w1img = w3img = w2img = CH*32768 ; himg = CH*36864

typedef __attribute__((ext_vector_type(8))) short bf16x8;
typedef __attribute__((ext_vector_type(8))) unsigned short u16x8;
typedef __attribute__((ext_vector_type(4))) float f32x4;

// async global->LDS, 16B per lane; LDS dst is wave-uniform base + lane*16
#define GL16(gp, lp) __builtin_amdgcn_global_load_lds( \
    (const __attribute__((address_space(1))) unsigned int*)(gp), \
    (__attribute__((address_space(3))) unsigned int*)(lp), 16, 0, 0)

__device__ __forceinline__ unsigned short f2bf(float f) {
  unsigned int u = __builtin_bit_cast(unsigned int, f);
  unsigned int r = u + 0x7FFFu + ((u >> 16) & 1u);
  return (unsigned short)(r >> 16);
}
__device__ __forceinline__ float bf2f(unsigned short s) {
  unsigned int u = ((unsigned int)s) << 16;
  return __builtin_bit_cast(float, u);
}
__device__ __forceinline__ void split2(float f, unsigned short& hi, unsigned short& lo) {
  hi = f2bf(f);
  lo = f2bf(f - bf2f(hi));
}

// ---------------- gating (unchanged) ----------------
__global__ __launch_bounds__(256) void gate_kernel(
    const float* __restrict__ x, const float* __restrict__ gw,
    int* __restrict__ sel, float* __restrict__ wts, int* __restrict__ counts)
{
  const int wave = threadIdx.x >> 6;
  const int lane = threadIdx.x & 63;
  const int t = blockIdx.x * 4 + wave;
  const float* xr = x + (size_t)t * DIM;
  float acc[NE] = {0.f, 0.f, 0.f, 0.f, 0.f, 0.f, 0.f, 0.f};
#pragma unroll 4
  for (int j = 0; j < DIM / 64; ++j) {
    const int d = lane + 64 * j;
    const float xv = xr[d];
#pragma unroll
    for (int e = 0; e < NE; ++e) acc[e] = fmaf(xv, gw[e * DIM + d], acc[e]);
  }
#pragma unroll
  for (int m = 32; m > 0; m >>= 1) {
#pragma unroll
    for (int e = 0; e < NE; ++e) acc[e] += __shfl_xor(acc[e], m, 64);
  }
  if (lane == 0) {
    float mx = acc[0];
#pragma unroll
    for (int e = 1; e < NE; ++e) mx = fmaxf(mx, acc[e]);
    float ex[NE];
#pragma unroll
    for (int e = 0; e < NE; ++e) ex[e] = __expf(acc[e] - mx);
    int e0 = 0; float p0 = ex[0];
#pragma unroll
    for (int e = 1; e < NE; ++e) if (ex[e] > p0) { p0 = ex[e]; e0 = e; }
    int e1 = -1; float p1 = -1.f;
#pragma unroll
    for (int e = 0; e < NE; ++e) if (e != e0 && ex[e] > p1) { p1 = ex[e]; e1 = e; }
    const float inv = 1.f / (p0 + p1);
    sel[2 * t + 0] = e0; sel[2 * t + 1] = e1;
    wts[2 * t + 0] = p0 * inv; wts[2 * t + 1] = p1 * inv;
    atomicAdd(&counts[e0], 1);
    atomicAdd(&counts[e1], 1);
  }
}

// ---------------- offsets (128-aligned regions) ----------------
__global__ void offsets_kernel(const int* __restrict__ counts,
                               int* __restrict__ offsets, int* __restrict__ cursors,
                               int* __restrict__ tile_e)
{
  if (threadIdx.x == 0 && blockIdx.x == 0) {
    int off = 0;
    for (int e = 0; e < NE; ++e) {
      offsets[e] = off;
      cursors[e] = off;
      off += (counts[e] + 127) & ~127;
    }
    offsets[NE] = off;
    for (int t = 0; t < NRT; ++t) {
      const int r = t * BM;
      int ee = 0;
      while (ee < NE - 1 && r >= offsets[ee + 1]) ++ee;
      tile_e[t] = ee;
    }
  }
}

// ---------------- scatter (unchanged) ----------------
__global__ __launch_bounds__(256) void scatter_kernel(
    const int* __restrict__ sel, const float* __restrict__ wts,
    int* __restrict__ cursors, int* __restrict__ atok, float* __restrict__ aw)
{
  const int t = blockIdx.x * 256 + threadIdx.x;
  if (t < T_TOK) {
#pragma unroll
    for (int k = 0; k < TOPK; ++k) {
      const int e = sel[2 * t + k];
      const int pos = atomicAdd(&cursors[e], 1);
      atok[pos] = t;
      aw[pos] = wts[2 * t + k];
    }
  }
}

// ---------------- prepass: x -> bf16 hi/lo row-major images ----------------
__global__ __launch_bounds__(256) void convert_x_kernel(
    const float* __restrict__ x, unsigned short* __restrict__ xhi,
    unsigned short* __restrict__ xlo)
{
  const size_t t = (size_t)blockIdx.x * 256 + threadIdx.x;   // 524288 units of 8
  const float* s = x + t * 8;
  u16x8 hi, lo;
#pragma unroll
  for (int q = 0; q < 8; ++q) {
    unsigned short h, l;
    split2(s[q], h, l);
    hi[q] = h; lo[q] = l;
  }
  *(u16x8*)&xhi[t * 8] = hi;
  *(u16x8*)&xlo[t * 8] = lo;
}

// ---------------- prepass: w1/w3 chunk -> frag-ordered tile image ----------------
// DEST-LINEAR remap (bit-identical image to round 7's): tile t = (e*nct1+ct)*32+kt,
// chunk c = nb*64+ks*16+n15; thread writes img[t*4096 + c*8] (hi) / +2048 (lo),
// reading 32B contiguous at row (ct*64+nb*16+n15), k = kt*32+ks*8.
// Wave writes 1KB hi + 1KB lo contiguous (was 16B scatter @256B stride).
__global__ __launch_bounds__(256) void convert_w13_kernel(
    const float* __restrict__ w, unsigned short* __restrict__ img,
    int hc0, int nct1)
{
  const int g = blockIdx.x * 256 + threadIdx.x;
  const int c = g & 255;
  const int t = g >> 8;
  const int n15 = c & 15, ks = (c >> 4) & 3, nb = c >> 6;
  const int kt = t & 31;
  const int ec = t >> 5;
  const int ct = ec % nct1, e = ec / nct1;
  const float* src = w + ((size_t)e * HID + hc0 + ct * 64 + nb * 16 + n15) * DIM + kt * 32 + ks * 8;
  u16x8 hi, lo;
#pragma unroll
  for (int q = 0; q < 8; ++q) {
    unsigned short h, l;
    split2(src[q], h, l);
    hi[q] = h; lo[q] = l;
  }
  *(u16x8*)&img[(size_t)t * 4096 + c * 8] = hi;
  *(u16x8*)&img[(size_t)t * 4096 + 2048 + c * 8] = lo;
}

// ---------------- prepass: w2 chunk -> frag-ordered tile image (unchanged; already dest-linear) ----------------
// tile idx = (e*16+ct2)*nkt2 + kt ; n = ct2*64+nb*16+n15 (DIM), k = kt*32+ks*8+j (chunk)
__global__ __launch_bounds__(256) void convert_w2_kernel(
    const float* __restrict__ w2, unsigned short* __restrict__ img,
    int hc0, int nkt2)
{
  const int f = blockIdx.x * 256 + threadIdx.x;
  const int n15 = f & 15;
  int t = f >> 4;
  const int ks = t & 3; t >>= 2;
  const int nb = t & 3; t >>= 2;
  const int kt = t % nkt2; t /= nkt2;
  const int ct2 = t & 15;
  const int e = t >> 4;
  const float* src = w2 + ((size_t)e * HID + hc0 + kt * 32 + ks * 8) * DIM + ct2 * 64 + nb * 16 + n15;
  u16x8 hi, lo;
#pragma unroll
  for (int q = 0; q < 8; ++q) {
    unsigned short h, l;
    split2(src[(size_t)q * DIM], h, l);
    hi[q] = h; lo[q] = l;
  }
  const size_t tile = ((size_t)(e * 16 + ct2) * nkt2 + kt) * 4096;
  const int off = nb * 512 + ks * 128 + n15 * 8;
  *(u16x8*)&img[tile + off] = hi;
  *(u16x8*)&img[tile + 2048 + off] = lo;
}

// ---------------- GEMM1: h = silu(x W1^T) * (x W3^T), pure MFMA loop ----------------
__global__ __launch_bounds__(256) void gemm1_kernel(
    const unsigned short* __restrict__ xhi, const unsigned short* __restrict__ xlo,
    const unsigned short* __restrict__ w1img, const unsigned short* __restrict__ w3img,
    const int* __restrict__ atok, const int* __restrict__ tile_e,
    const int* __restrict__ offsets, unsigned short* __restrict__ himg, int nct1)
{
  __shared__ __align__(16) unsigned short sAh[4096], sAl[4096];
  __shared__ __align__(16) unsigned short sB1h[2048], sB1l[2048], sB3h[2048], sB3l[2048];
  __shared__ int sToks[BM];

  const int orig = blockIdx.x;
  const int wg = (orig & 7) * (gridDim.x >> 3) + (orig >> 3);   // XCD-chunked (grid%8==0)
  const int ct = wg / NRT, rt = wg % NRT;
  if (rt * BM >= offsets[NE]) return;       // all-pad row tile: nothing downstream reads it
  const int nkt2 = nct1 * 2;
  const int tid = threadIdx.x, lane = tid & 63;
  const int wv = tid >> 6, wr = wv >> 1, wc = wv & 1;
  const int e = tile_e[rt];

  if (tid < BM) {
    const int tk = atok[rt * BM + tid];
    sToks[tid] = tk < 0 ? 0 : tk;
  }
  __syncthreads();

  // per-lane gather sources for A (ushort offsets into x images)
  const int rb0 = wv * 2;
  size_t asrc[2];
#pragma unroll
  for (int i = 0; i < 2; ++i) {
    const int row = (rb0 + i) * 16 + (lane & 15);
    asrc[i] = (size_t)sToks[row] * DIM + ((lane >> 4) * 8);
  }
  const size_t btile0 = ((size_t)(e * nct1 + ct) * 32) * 4096;
  const size_t boff = btile0 + wv * 512 + (size_t)lane * 8;   // hi; +2048 for lo

  const f32x4 vz = {0.f, 0.f, 0.f, 0.f};
  f32x4 acc1[4][2], acc3[4][2];
#pragma unroll
  for (int i = 0; i < 4; ++i)
#pragma unroll
    for (int j = 0; j < 2; ++j) { acc1[i][j] = vz; acc3[i][j] = vz; }

  for (int kt = 0; kt < DIM / BK; ++kt) {
    __syncthreads();                       // prev frag reads done before overwrite
#pragma unroll
    for (int i = 0; i < 2; ++i) {
      GL16(xhi + asrc[i] + kt * 32, &sAh[(rb0 + i) * 512]);
      GL16(xlo + asrc[i] + kt * 32, &sAl[(rb0 + i) * 512]);
    }
    const size_t bk = boff + (size_t)kt * 4096;
    GL16(w1img + bk,        &sB1h[wv * 512]);
    GL16(w1img + bk + 2048, &sB1l[wv * 512]);
    GL16(w3img + bk,        &sB3h[wv * 512]);
    GL16(w3img + bk + 2048, &sB3l[wv * 512]);
    __syncthreads();                       // drains vmcnt -> LDS writes visible

    bf16x8 ah[4], al[4], g1h[2], g1l[2], g3h[2], g3l[2];
#pragma unroll
    for (int ar = 0; ar < 4; ++ar) {
      const int rb = wr * 4 + ar;
      ah[ar] = *(const bf16x8*)&sAh[rb * 512 + lane * 8];
      al[ar] = *(const bf16x8*)&sAl[rb * 512 + lane * 8];
    }
#pragma unroll
    for (int bc = 0; bc < 2; ++bc) {
      const int cb = wc * 2 + bc;
      g1h[bc] = *(const bf16x8*)&sB1h[cb * 512 + lane * 8];
      g1l[bc] = *(const bf16x8*)&sB1l[cb * 512 + lane * 8];
      g3h[bc] = *(const bf16x8*)&sB3h[cb * 512 + lane * 8];
      g3l[bc] = *(const bf16x8*)&sB3l[cb * 512 + lane * 8];
    }
#pragma unroll
    for (int ar = 0; ar < 4; ++ar)
#pragma unroll
      for (int bc = 0; bc < 2; ++bc) {
        acc1[ar][bc] = __builtin_amdgcn_mfma_f32_16x16x32_bf16(ah[ar], g1h[bc], acc1[ar][bc], 0, 0, 0);
        acc1[ar][bc] = __builtin_amdgcn_mfma_f32_16x16x32_bf16(ah[ar], g1l[bc], acc1[ar][bc], 0, 0, 0);
        acc1[ar][bc] = __builtin_amdgcn_mfma_f32_16x16x32_bf16(al[ar], g1h[bc], acc1[ar][bc], 0, 0, 0);
        acc3[ar][bc] = __builtin_amdgcn_mfma_f32_16x16x32_bf16(ah[ar], g3h[bc], acc3[ar][bc], 0, 0, 0);
        acc3[ar][bc] = __builtin_amdgcn_mfma_f32_16x16x32_bf16(ah[ar], g3l[bc], acc3[ar][bc], 0, 0, 0);
        acc3[ar][bc] = __builtin_amdgcn_mfma_f32_16x16x32_bf16(al[ar], g3h[bc], acc3[ar][bc], 0, 0, 0);
      }
  }

  // epilogue: silu*u, split, write h as frag-ordered hi/lo tiles for gemm2's A
  const size_t hbase = ((size_t)rt * nkt2 + (ct * 2 + wc)) * 8192;   // tile pair = 8192 us
#pragma unroll
  for (int ar = 0; ar < 4; ++ar)
#pragma unroll
    for (int bc = 0; bc < 2; ++bc)
#pragma unroll
      for (int r = 0; r < 4; ++r) {
        const float g = acc1[ar][bc][r];
        const float u = acc3[ar][bc][r];
        const float s = g / (1.f + __expf(-g));
        unsigned short h_, l_;
        split2(s * u, h_, l_);
        const int idx = (wr * 4 + ar) * 512 + (bc * 2 + ((lane >> 3) & 1)) * 128
                      + ((lane >> 4) * 4 + r) * 8 + (lane & 7);
        himg[hbase + idx] = h_;
        himg[hbase + 4096 + idx] = l_;
      }
}

// ---------------- GEMM2: y += (h W2) * route_weight ----------------
__global__ __launch_bounds__(256) void gemm2_kernel(
    const unsigned short* __restrict__ himg, const unsigned short* __restrict__ w2img,
    const int* __restrict__ atok, const float* __restrict__ aw,
    const int* __restrict__ tile_e, const int* __restrict__ offsets,
    float* __restrict__ y, int nkt2)
{
  __shared__ __align__(16) unsigned short sAh[4096], sAl[4096];
  __shared__ __align__(16) unsigned short sBh[2048], sBl[2048];

  const int orig = blockIdx.x;
  const int wg = (orig & 7) * (gridDim.x >> 3) + (orig >> 3);
  const int ct2 = wg / NRT, rt = wg % NRT;
  if (rt * BM >= offsets[NE]) return;       // all-pad row tile
  const int tid = threadIdx.x, lane = tid & 63;
  const int wv = tid >> 6, wr = wv >> 1, wc = wv & 1;
  const int e = tile_e[rt];

  const int rb0 = wv * 2;
  const size_t atile0 = (size_t)rt * nkt2 * 8192;
  const size_t btile0 = ((size_t)(e * 16 + ct2) * nkt2) * 4096;
  const size_t lane8 = (size_t)lane * 8;

  const f32x4 vz = {0.f, 0.f, 0.f, 0.f};
  f32x4 acc[4][2];
#pragma unroll
  for (int i = 0; i < 4; ++i)
#pragma unroll
    for (int j = 0; j < 2; ++j) acc[i][j] = vz;

  for (int kt = 0; kt < nkt2; ++kt) {
    __syncthreads();
    const size_t ab = atile0 + (size_t)kt * 8192;
#pragma unroll
    for (int i = 0; i < 2; ++i) {
      GL16(himg + ab + (rb0 + i) * 512 + lane8,        &sAh[(rb0 + i) * 512]);
      GL16(himg + ab + 4096 + (rb0 + i) * 512 + lane8, &sAl[(rb0 + i) * 512]);
    }
    const size_t bb = btile0 + (size_t)kt * 4096 + wv * 512 + lane8;
    GL16(w2img + bb,        &sBh[wv * 512]);
    GL16(w2img + bb + 2048, &sBl[wv * 512]);
    __syncthreads();

    bf16x8 ah[4], al[4], bh_[2], bl_[2];
#pragma unroll
    for (int ar = 0; ar < 4; ++ar) {
      const int rb = wr * 4 + ar;
      ah[ar] = *(const bf16x8*)&sAh[rb * 512 + lane * 8];
      al[ar] = *(const bf16x8*)&sAl[rb * 512 + lane * 8];
    }
#pragma unroll
    for (int bc = 0; bc < 2; ++bc) {
      const int cb = wc * 2 + bc;
      bh_[bc] = *(const bf16x8*)&sBh[cb * 512 + lane * 8];
      bl_[bc] = *(const bf16x8*)&sBl[cb * 512 + lane * 8];
    }
#pragma unroll
    for (int ar = 0; ar < 4; ++ar)
#pragma unroll
      for (int bc = 0; bc < 2; ++bc) {
        acc[ar][bc] = __builtin_amdgcn_mfma_f32_16x16x32_bf16(ah[ar], bh_[bc], acc[ar][bc], 0, 0, 0);
        acc[ar][bc] = __builtin_amdgcn_mfma_f32_16x16x32_bf16(ah[ar], bl_[bc], acc[ar][bc], 0, 0, 0);
        acc[ar][bc] = __builtin_amdgcn_mfma_f32_16x16x32_bf16(al[ar], bh_[bc], acc[ar][bc], 0, 0, 0);
      }
  }

#pragma unroll
  for (int ar = 0; ar < 4; ++ar)
#pragma unroll
    for (int r = 0; r < 4; ++r) {
      const int grow = rt * BM + wr * 64 + ar * 16 + (lane >> 4) * 4 + r;
      const int tok = atok[grow];
      if (tok >= 0) {
        const float wgt = aw[grow];
#pragma unroll
        for (int bc = 0; bc < 2; ++bc) {
          const int col = ct2 * BN + wc * 32 + bc * 16 + (lane & 15);
          atomicAdd(y + (size_t)tok * DIM + col, acc[ar][bc][r] * wgt);
        }
      }
    }
}

// ---------------- launch ----------------
extern "C" void kernel_launch(void* const* d_in, const int* in_sizes, int n_in,
                              void* d_out, int out_size, void* d_ws, size_t ws_size,
                              hipStream_t stream) {
  const float* x  = (const float*)d_in[0];
  const float* w1 = (const float*)d_in[1];
  const float* w2 = (const float*)d_in[2];
  const float* w3 = (const float*)d_in[3];
  const float* gw = (const float*)d_in[4];
  float* y = (float*)d_out;

  char* ws = (char*)d_ws;
  int*   counts  = (int*)(ws + WS_COUNTS);
  int*   cursors = (int*)(ws + WS_CURSORS);
  int*   offsets = (int*)(ws + WS_OFFSETS);
  int*   tile_e  = (int*)(ws + WS_TILE_E);
  int*   sel     = (int*)(ws + WS_SEL);
  float* wts     = (float*)(ws + WS_WTS);
  int*   atok    = (int*)(ws + WS_ATOK);
  float* aw      = (float*)(ws + WS_AW);
  unsigned short* xhi = (unsigned short*)(ws + WS_XHI);
  unsigned short* xlo = (unsigned short*)(ws + WS_XLO);

  // largest hidden-chunk (divides 2816, %64==0) fitting the image workspace
  static const int chs[6] = {2816, 1408, 704, 256, 128, 64};
  int CH = 64;
  for (int i = 0; i < 6; ++i) {
    const size_t need = (size_t)WS_IMG + (size_t)chs[i] * 135168ull;
    if (need <= ws_size) { CH = chs[i]; break; }
  }
  const int nct1 = CH / 64, nkt2 = CH / 32;
  const size_t wimg_b = (size_t)CH * 32768ull;
  unsigned short* w1img = (unsigned short*)(ws + WS_IMG);
  unsigned short* w3img = (unsigned short*)(ws + WS_IMG + wimg_b);
  unsigned short* w2img = (unsigned short*)(ws + WS_IMG + 2 * wimg_b);
  unsigned short* himg  = (unsigned short*)(ws + WS_IMG + 3 * wimg_b);

  hipMemsetAsync(counts, 0, 8 * sizeof(int), stream);
  hipMemsetAsync(atok, 0xFF, CAP * sizeof(int), stream);
  hipMemsetAsync(y, 0, (size_t)T_TOK * DIM * sizeof(float), stream);

  gate_kernel<<<T_TOK / 4, 256, 0, stream>>>(x, gw, sel, wts, counts);
  offsets_kernel<<<1, 64, 0, stream>>>(counts, offsets, cursors, tile_e);
  scatter_kernel<<<T_TOK / 256, 256, 0, stream>>>(sel, wts, cursors, atok, aw);
  convert_x_kernel<<<(T_TOK * DIM / 8) / 256, 256, 0, stream>>>(x, xhi, xlo);

  for (int hc0 = 0; hc0 < HID; hc0 += CH) {
    const int wblk = 8 * nct1 * 32;           // one 256-thread block per tile pair
    convert_w13_kernel<<<wblk, 256, 0, stream>>>(w1, w1img, hc0, nct1);
    convert_w13_kernel<<<wblk, 256, 0, stream>>>(w3, w3img, hc0, nct1);
    convert_w2_kernel<<<128 * nkt2, 256, 0, stream>>>(w2, w2img, hc0, nkt2);
    gemm1_kernel<<<NRT * nct1, 256, 0, stream>>>(xhi, xlo, w1img, w3img, atok, tile_e, offsets, himg, nct1);
    gemm2_kernel<<<NRT * 16, 256, 0, stream>>>(himg, w2img, atok, aw, tile_e, offsets, y, nkt2);
  }
}